// Round 10
// baseline (343.648 us; speedup 1.0000x reference)
//
#include <hip/hip_runtime.h>
#include <math.h>

#define HH 128
#define WW 128
#define BB 4
#define HW (HH*WW)

typedef unsigned short u16;
typedef unsigned int u32;
typedef __bf16 bf16x8 __attribute__((ext_vector_type(8)));
typedef float f32x4 __attribute__((ext_vector_type(4)));

__device__ __forceinline__ u16 f2bf(float x) {
    u32 u = __float_as_uint(x);
    return (u16)((u + 0x7fffu + ((u >> 16) & 1u)) >> 16);
}
__device__ __forceinline__ float bf2f(u16 h) {
    return __uint_as_float(((u32)h) << 16);
}
__device__ __forceinline__ bf16x8 ld8(const u16* p) {
    union { uint4 u; bf16x8 v; } c;
    c.u = *(const uint4*)p;
    return c.v;
}
__device__ __forceinline__ bf16x8 cvt8(uint4 u) {
    union { uint4 u; bf16x8 v; } c;
    c.u = u;
    return c.v;
}

// ---------------------------------------------------------------------------
// Weight split-prep: src [OC][CIN][3][3] f32 -> dh/dl [OCpad][9][CINpad] bf16
// ---------------------------------------------------------------------------
__global__ void split_w_k(const float* __restrict__ src, u16* __restrict__ dh,
                          u16* __restrict__ dl, int OC, int OCpad, int CIN, int CINpad)
{
    const int i = blockIdx.x * 256 + threadIdx.x;
    const int tot = OCpad * 9 * CINpad;
    if (i >= tot) return;
    const int oc = i / (9 * CINpad);
    const int r = i - oc * 9 * CINpad;
    const int tap = r / CINpad;
    const int cin = r - tap * CINpad;
    float v = 0.f;
    if (oc < OC && cin < CIN) v = src[((size_t)oc * CIN + cin) * 9 + tap];
    const u16 h = f2bf(v);
    dh[i] = h;
    dl[i] = f2bf(v - bf2f(h));
}

__global__ void pad_bias_k(const float* __restrict__ b, float* __restrict__ bp)
{
    const int i = blockIdx.x * 256 + threadIdx.x;
    if (i < 256) bp[i] = (i < 216) ? b[i] : 0.f;
}

// ---------------------------------------------------------------------------
// Deform weight [O=64][C=64][3][3] -> bf16 A-fragments for 16x16x32 MFMA:
// Apack u16[kk(18)][fq(4)][m(4)][fr(16)][jj(8)]
// ---------------------------------------------------------------------------
__global__ void pack_dw_k(const float* __restrict__ wt, u16* __restrict__ Apack)
{
    const int i = blockIdx.x * 256 + threadIdx.x;   // 36864
    if (i >= 36864) return;
    const int jj = i & 7;
    const int fr = (i >> 3) & 15;
    const int m  = (i >> 7) & 3;
    const int fq = (i >> 9) & 3;
    const int kk = i >> 11;
    const int oc = m * 16 + fr;
    const int j  = kk * 32 + fq * 8 + jj;
    const int tap = j >> 3, c = j & 7;
    const int g = tap / 9, kt = tap - g * 9;
    const int ch = g * 8 + c;
    Apack[i] = f2bf(wt[((size_t)oc * 64 + ch) * 9 + kt]);
}

// ---------------------------------------------------------------------------
// Pack concat(xw 64, xc 64, flow 2, zeros) into split-bf16 records:
// dst[b*HW+px][CREC*2 u16], ch c at (c>>5)*64 + ((c>>3)&3)*16 + (c&7), lo +8.
// ---------------------------------------------------------------------------
template<int CREC>
__global__ __launch_bounds__(256) void pack_x_k(
    const float* __restrict__ A, const float* __restrict__ B2,
    const float* __restrict__ C3, u16* __restrict__ dst)
{
    const int i = blockIdx.x * 256 + threadIdx.x;   // b*HW + px
    const int b = i >> 14;
    const int px = i & 16383;
    u16* rec = dst + (size_t)i * (CREC * 2);

#pragma unroll
    for (int g = 0; g < CREC / 32; ++g) {
#pragma unroll
        for (int cb = 0; cb < 4; ++cb) {
            u32 hwv[4], lwv[4];
#pragma unroll
            for (int p = 0; p < 4; ++p) {
                float v[2];
#pragma unroll
                for (int e = 0; e < 2; ++e) {
                    const int c = g * 32 + cb * 8 + p * 2 + e;
                    float vv;
                    if (c < 64)       vv = A[((size_t)(b * 64 + c)) * HW + px];
                    else if (c < 128) vv = B2[((size_t)(b * 64 + c - 64)) * HW + px];
                    else if (c < 130) vv = C3[((size_t)(b * 2 + c - 128)) * HW + px];
                    else              vv = 0.f;
                    v[e] = vv;
                }
                const u16 h0 = f2bf(v[0]), h1 = f2bf(v[1]);
                const u16 l0 = f2bf(v[0] - bf2f(h0)), l1 = f2bf(v[1] - bf2f(h1));
                hwv[p] = (u32)h0 | ((u32)h1 << 16);
                lwv[p] = (u32)l0 | ((u32)l1 << 16);
            }
            uint4 H; H.x = hwv[0]; H.y = hwv[1]; H.z = hwv[2]; H.w = hwv[3];
            uint4 L; L.x = lwv[0]; L.y = lwv[1]; L.z = lwv[2]; L.w = lwv[3];
            *(uint4*)(rec + g * 64 + cb * 16)     = H;
            *(uint4*)(rec + g * 64 + cb * 16 + 8) = L;
        }
    }
}

// ---------------------------------------------------------------------------
// MFMA 3x3 conv on packed split-bf16 input.
// MODE 0 (conv1-3): tile 16(w)x4(h), 64 oc; wave wv = m-tile wv, all 4 rows.
//   acc0[4] = 16 VGPR. LDS 29.4 KB. PACKOUT fuses lrelu + split-bf16 repack.
// MODE 1 (conv4): tile 16(w)x8(h), 128 oc (grid.y slices); wave (mg,rg);
//   rolled tap-pair loop with ping/pong A prefetch; __launch_bounds__(256,1)
//   [(256,2) caps VGPR at 128 -> spill, proven R7/R8].
// ---------------------------------------------------------------------------
template<int NCHUNK, int KGLAST, int MODE, bool RELU, bool PACKOUT, int MINW>
__global__ __launch_bounds__(256, MINW) void conv_pk_k(
    const u16* __restrict__ Xp, const u16* __restrict__ Wh, const u16* __restrict__ Wl,
    const float* __restrict__ bias, float* __restrict__ outf, u16* __restrict__ outp,
    int OCreal)
{
    const int ROWS = (MODE == 1) ? 8 : 4;
    const int NPX = (ROWS + 2) * 18;
    __shared__ u16 Xs[NPX * 136];
    const int CINpad = (NCHUNK - 1) * 64 + KGLAST * 32;
    const int CRECU16 = CINpad * 2;

    const int tile = blockIdx.x;
    const int h0 = (tile >> 3) * ROWS;
    const int w0 = (tile & 7) * 16;
    const int b = blockIdx.z;
    const int t = threadIdx.x;
    const int lane = t & 63, wv = t >> 6;
    const int fr = lane & 15, fq = lane >> 4;

    const int mg = wv >> 1, rg = wv & 1;
    const int mbase = (MODE == 1) ? (blockIdx.y * 8 + mg * 4) : 0;

    f32x4 acc0[4];
    f32x4 acc1[4][4];
    if (MODE == 0) {
        const float4 bv = *(const float4*)(bias + wv * 16 + 4 * fq);
#pragma unroll
        for (int n = 0; n < 4; ++n) {
            acc0[n][0] = bv.x; acc0[n][1] = bv.y; acc0[n][2] = bv.z; acc0[n][3] = bv.w;
        }
    } else {
#pragma unroll
        for (int m = 0; m < 4; ++m) {
            const float4 bv = *(const float4*)(bias + (mbase + m) * 16 + 4 * fq);
#pragma unroll
            for (int n = 0; n < 4; ++n) {
                acc1[m][n][0] = bv.x; acc1[m][n][1] = bv.y;
                acc1[m][n][2] = bv.z; acc1[m][n][3] = bv.w;
            }
        }
    }

    const u16* WhL = Wh + (size_t)fr * 9 * CINpad + 8 * fq;
    const u16* WlL = Wl + (size_t)fr * 9 * CINpad + 8 * fq;

#pragma unroll
    for (int chunk = 0; chunk < NCHUNK; ++chunk) {
        const int nkg = (chunk == NCHUNK - 1) ? KGLAST : 2;
        const int nu = nkg * 8;
        __syncthreads();
        for (int s = t; s < NPX * nu; s += 256) {
            const int px = s / nu, o = s - px * nu;
            const int hy = px / 18, hx = px - hy * 18;
            const int gy = h0 + hy - 1, gx = w0 + hx - 1;
            uint4 v; v.x = 0; v.y = 0; v.z = 0; v.w = 0;
            if (gy >= 0 && gy < HH && gx >= 0 && gx < WW)
                v = *(const uint4*)(Xp + ((size_t)(b * HW + gy * WW + gx)) * CRECU16
                                       + chunk * 128 + o * 8);
            *(uint4*)(Xs + px * 136 + o * 8) = v;
        }
        __syncthreads();

        if (MODE == 0) {
#pragma unroll
            for (int tap = 0; tap < 9; ++tap) {
                const int ky = tap / 3, kx = tap % 3;
#pragma unroll
                for (int kg = 0; kg < 2; ++kg) {
                    if (kg >= nkg) break;
                    const size_t off = (size_t)(wv * 144 + tap) * CINpad + chunk * 64 + kg * 32;
                    const bf16x8 Ah = ld8(WhL + off);
                    const bf16x8 Al = ld8(WlL + off);
#pragma unroll
                    for (int n = 0; n < 4; ++n) {
                        const int hp = (n + ky) * 18 + fr + kx;
                        const u16* Bp = Xs + hp * 136 + kg * 64 + fq * 16;
                        const bf16x8 Bh = ld8(Bp);
                        const bf16x8 Bl = ld8(Bp + 8);
                        acc0[n] = __builtin_amdgcn_mfma_f32_16x16x32_bf16(Ah, Bh, acc0[n], 0, 0, 0);
                        acc0[n] = __builtin_amdgcn_mfma_f32_16x16x32_bf16(Ah, Bl, acc0[n], 0, 0, 0);
                        acc0[n] = __builtin_amdgcn_mfma_f32_16x16x32_bf16(Al, Bh, acc0[n], 0, 0, 0);
                    }
                }
            }
        } else {
            auto PF = [&](int tap, bf16x8 (&Dh)[8], bf16x8 (&Dl)[8]) {
#pragma unroll
                for (int kg = 0; kg < 2; ++kg)
#pragma unroll
                    for (int m = 0; m < 4; ++m) {
                        const size_t off = (size_t)((mbase + m) * 144 + tap) * CINpad
                                         + chunk * 64 + kg * 32;
                        Dh[kg * 4 + m] = ld8(WhL + off);
                        Dl[kg * 4 + m] = ld8(WlL + off);
                    }
            };
            auto CMP = [&](int tap, bf16x8 (&Dh)[8], bf16x8 (&Dl)[8]) {
                const int ky = tap / 3, kx = tap - 3 * ky;
#pragma unroll
                for (int kg = 0; kg < 2; ++kg) {
#pragma unroll
                    for (int n = 0; n < 4; ++n) {
                        const int hp = (rg * 4 + n + ky) * 18 + fr + kx;
                        const u16* Bp = Xs + hp * 136 + kg * 64 + fq * 16;
                        const bf16x8 Bh = ld8(Bp);
                        const bf16x8 Bl = ld8(Bp + 8);
#pragma unroll
                        for (int m = 0; m < 4; ++m) {
                            acc1[m][n] = __builtin_amdgcn_mfma_f32_16x16x32_bf16(Dh[kg * 4 + m], Bh, acc1[m][n], 0, 0, 0);
                            acc1[m][n] = __builtin_amdgcn_mfma_f32_16x16x32_bf16(Dh[kg * 4 + m], Bl, acc1[m][n], 0, 0, 0);
                            acc1[m][n] = __builtin_amdgcn_mfma_f32_16x16x32_bf16(Dl[kg * 4 + m], Bh, acc1[m][n], 0, 0, 0);
                        }
                    }
                }
            };

            bf16x8 PaH[8], PaL[8], PbH[8], PbL[8];
            PF(0, PaH, PaL);
#pragma unroll 1
            for (int tp = 0; tp < 4; ++tp) {
                PF(2 * tp + 1, PbH, PbL);
                CMP(2 * tp, PaH, PaL);
                PF(2 * tp + 2, PaH, PaL);
                CMP(2 * tp + 1, PbH, PbL);
            }
            CMP(8, PaH, PaL);
        }
    }

    if (MODE == 1) {
#pragma unroll
        for (int m = 0; m < 4; ++m)
#pragma unroll
            for (int n = 0; n < 4; ++n)
#pragma unroll
                for (int i = 0; i < 4; ++i) {
                    const int oc = (mbase + m) * 16 + 4 * fq + i;
                    if (oc < OCreal) {
                        float v = acc1[m][n][i];
                        if (RELU) v = (v >= 0.f) ? v : 0.1f * v;
                        outf[((size_t)(b * OCreal + oc)) * HW + (h0 + rg * 4 + n) * WW + w0 + fr] = v;
                    }
                }
    } else if (!PACKOUT) {
#pragma unroll
        for (int n = 0; n < 4; ++n)
#pragma unroll
            for (int i = 0; i < 4; ++i) {
                const int oc = wv * 16 + 4 * fq + i;
                if (oc < OCreal) {
                    float v = acc0[n][i];
                    if (RELU) v = (v >= 0.f) ? v : 0.1f * v;
                    outf[((size_t)(b * OCreal + oc)) * HW + (h0 + n) * WW + w0 + fr] = v;
                }
            }
    } else {
        __syncthreads();
        const int coff = (wv >> 1) * 64 + (((wv << 1) + (fq >> 1)) & 3) * 16 + ((fq & 1) << 2);
#pragma unroll
        for (int n = 0; n < 4; ++n) {
            u16 hh[4], ll[4];
#pragma unroll
            for (int i = 0; i < 4; ++i) {
                float v = acc0[n][i];
                if (RELU) v = (v >= 0.f) ? v : 0.1f * v;
                hh[i] = f2bf(v);
                ll[i] = f2bf(v - bf2f(hh[i]));
            }
            uint2 H, L;
            H.x = (u32)hh[0] | ((u32)hh[1] << 16);
            H.y = (u32)hh[2] | ((u32)hh[3] << 16);
            L.x = (u32)ll[0] | ((u32)ll[1] << 16);
            L.y = (u32)ll[2] | ((u32)ll[3] << 16);
            const int pxe = n * 16 + fr;
            u16* E = Xs + pxe * 136 + coff;
            *(uint2*)E = H;
            *(uint2*)(E + 8) = L;
        }
        __syncthreads();
        for (int i = t; i < 1024; i += 256) {
            const int px = i >> 4, o = i & 15;
            const uint4 v = *(const uint4*)(Xs + px * 136 + o * 8);
            const int gp = (h0 + (px >> 4)) * WW + w0 + (px & 15);
            *(uint4*)(outp + ((size_t)(b * HW + gp)) * 128 + o * 8) = v;
        }
    }
}

// ---------------------------------------------------------------------------
// x [b][64][HW] -> xq [b][16][HW] float4 channel-quads (deform gather layout)
// ---------------------------------------------------------------------------
__global__ __launch_bounds__(256) void transpose_xq_k(
    const float* __restrict__ x, float4* __restrict__ xq)
{
    const int i = blockIdx.x * 256 + threadIdx.x;
    const int pix = i & (HW - 1);
    const int q = (i >> 14) & 15;
    const int b = i >> 18;
    const float* xp = x + ((size_t)(b * 64 + q * 4)) * HW + pix;
    float4 v;
    v.x = xp[0]; v.y = xp[HW]; v.z = xp[2 * HW]; v.w = xp[3 * HW];
    xq[(size_t)(b * 16 + q) * HW + pix] = v;
}

__device__ __forceinline__ unsigned pk_bf16(float lo, float hi) {
    unsigned a = __float_as_uint(lo), b = __float_as_uint(hi);
    return ((a + 0x8000u) >> 16) | ((b + 0x8000u) & 0xffff0000u);
}

// ---------------------------------------------------------------------------
// Fused deform, 16-px blocks for 2x gather parallelism.
// Phase 1: thread = (px 0..15, g 0..7, kh 0..1); kh=0 -> taps 0..3,
//          kh=1 -> taps 4..8. Bilinear samples -> bf16 into LDS sv[16][584].
// Phase 2: MFMA: wave wv = m-tile (16 oc), single 16-px N-tile, K=18 chunks.
// LDS 18.7 KB -> up to 8 blocks/CU if VGPR <= 64.
// ---------------------------------------------------------------------------
__global__ __launch_bounds__(256, 4) void deform_fused_k(
    const float4* __restrict__ xq, const float* __restrict__ o4,
    const float* __restrict__ flow, const uint4* __restrict__ Apack,
    const float* __restrict__ bias, float* __restrict__ out)
{
    __shared__ u16 sv[16 * 584];   // 18,688 B

    const int bid = blockIdx.x;    // 4096
    const int b = bid >> 10;
    const int pix0 = (bid & 1023) << 4;
    const int t = threadIdx.x;

    // ---------------- phase 1: gather -------------------------------------
    {
        const int px = t & 15, gk = t >> 4;
        const int g = gk >> 1, kh = gk & 1;
        const int kbase = kh * 4;          // kh=0: taps 0..3, kh=1: taps 4..8
        const int pix = pix0 + px;
        const int h = pix >> 7, w = pix & (WW - 1);
        const float fy = flow[((size_t)b * 2 + 1) * HW + pix];
        const float fx = flow[((size_t)b * 2 + 0) * HW + pix];
        const float* ob = o4 + (size_t)b * 216 * HW + pix;
        const float4* q0 = xq + (size_t)(b * 16 + g * 2) * HW;
        const float4* q1 = q0 + HW;

        int   code[5];
        float w00[5], w01[5], w10[5], w11[5];

#pragma unroll
        for (int j = 0; j < 5; ++j) {
            if (j == 4 && !kh) break;
            const int k = kbase + j;
            const float oy = ob[(size_t)(g * 18 + k * 2) * HW];
            const float ox = ob[(size_t)(g * 18 + k * 2 + 1) * HW];
            float mm = ob[(size_t)(144 + g * 9 + k) * HW];
            mm = __builtin_amdgcn_rcpf(1.f + __expf(-mm));

            const float ay = fabsf(oy), ax = fabsf(ox);
            const float ey = __expf(-2.f * ay), ex = __expf(-2.f * ax);
            float ty = (1.f - ey) * __builtin_amdgcn_rcpf(1.f + ey);
            float tx = (1.f - ex) * __builtin_amdgcn_rcpf(1.f + ex);
            ty = copysignf(ty, oy); tx = copysignf(tx, ox);

            const float ppy = 10.f * ty + fy + (float)(h + k / 3 - 1);
            const float ppx = 10.f * tx + fx + (float)(w + k % 3 - 1);

            const float y0f = floorf(ppy), x0f = floorf(ppx);
            const float ly = ppy - y0f, lx = ppx - x0f;
            const int iy0 = (int)y0f, ix0 = (int)x0f;
            const int iy1 = iy0 + 1,  ix1 = ix0 + 1;

            const float vy0 = (iy0 >= 0 && iy0 < HH) ? 1.f : 0.f;
            const float vy1 = (iy1 >= 0 && iy1 < HH) ? 1.f : 0.f;
            const float vx0 = (ix0 >= 0 && ix0 < WW) ? 1.f : 0.f;
            const float vx1 = (ix1 >= 0 && ix1 < WW) ? 1.f : 0.f;

            const int cy0 = min(max(iy0, 0), HH - 1);
            const int cy1 = min(max(iy1, 0), HH - 1);
            const int cx0 = min(max(ix0, 0), WW - 1);
            const int cx1 = min(max(ix1, 0), WW - 1);

            w00[j] = (1.f - ly) * (1.f - lx) * vy0 * vx0 * mm;
            w01[j] = (1.f - ly) * lx         * vy0 * vx1 * mm;
            w10[j] = ly         * (1.f - lx) * vy1 * vx0 * mm;
            w11[j] = ly         * lx         * vy1 * vx1 * mm;

            code[j] = (cy0 * WW + cx0) | ((cx1 - cx0) << 14) | ((cy1 - cy0) << 15);
        }

        u16* svp = sv + px * 584 + g * 72 + kbase * 8;
#pragma unroll
        for (int j = 0; j < 5; ++j) {
            if (j == 4 && !kh) break;
            const int i00 = code[j] & 16383;
            const int i01 = i00 + ((code[j] >> 14) & 1);
            const int i10 = i00 + (((code[j] >> 15) & 1) << 7);
            const int i11 = i10 + ((code[j] >> 14) & 1);

            const float4 a0 = q0[i00], a1 = q1[i00];
            const float4 b0 = q0[i01], b1 = q1[i01];
            const float4 c0 = q0[i10], c1 = q1[i10];
            const float4 d0 = q0[i11], d1 = q1[i11];
            const float W00 = w00[j], W01 = w01[j], W10 = w10[j], W11 = w11[j];

            float s0 = W00 * a0.x + W01 * b0.x + W10 * c0.x + W11 * d0.x;
            float s1 = W00 * a0.y + W01 * b0.y + W10 * c0.y + W11 * d0.y;
            float s2 = W00 * a0.z + W01 * b0.z + W10 * c0.z + W11 * d0.z;
            float s3 = W00 * a0.w + W01 * b0.w + W10 * c0.w + W11 * d0.w;
            float s4 = W00 * a1.x + W01 * b1.x + W10 * c1.x + W11 * d1.x;
            float s5 = W00 * a1.y + W01 * b1.y + W10 * c1.y + W11 * d1.y;
            float s6 = W00 * a1.z + W01 * b1.z + W10 * c1.z + W11 * d1.z;
            float s7 = W00 * a1.w + W01 * b1.w + W10 * c1.w + W11 * d1.w;

            uint4 P;
            P.x = pk_bf16(s0, s1);
            P.y = pk_bf16(s2, s3);
            P.z = pk_bf16(s4, s5);
            P.w = pk_bf16(s6, s7);
            *(uint4*)(svp + (size_t)j * 8) = P;
        }
    }
    __syncthreads();

    // ---------------- phase 2: MFMA (wave wv = M-tile, 16 px) --------------
    {
        const int lane = t & 63, wv = t >> 6;
        const int fr = lane & 15, fq = lane >> 4;

        f32x4 acc;
        acc[0] = 0.f; acc[1] = 0.f; acc[2] = 0.f; acc[3] = 0.f;

#pragma unroll
        for (int kk = 0; kk < 18; ++kk) {
            const bf16x8 A = cvt8(Apack[((kk * 4 + fq) * 4 + wv) * 16 + fr]);
            const bf16x8 Bf = ld8(sv + (size_t)fr * 584 + kk * 32 + fq * 8);
            acc = __builtin_amdgcn_mfma_f32_16x16x32_bf16(A, Bf, acc, 0, 0, 0);
        }

        const float4 bv = *(const float4*)(bias + wv * 16 + 4 * fq);
        const float bb[4] = { bv.x, bv.y, bv.z, bv.w };
#pragma unroll
        for (int i = 0; i < 4; ++i) {
            const int oc = wv * 16 + 4 * fq + i;
            out[((size_t)b * 64 + oc) * HW + pix0 + fr] = acc[i] + bb[i];
        }
    }
}

// ---------------------------------------------------------------------------
extern "C" void kernel_launch(void* const* d_in, const int* in_sizes, int n_in,
                              void* d_out, int out_size, void* d_ws, size_t ws_size,
                              hipStream_t stream)
{
    const float* x     = (const float*)d_in[0];
    const float* xw    = (const float*)d_in[1];
    const float* xc    = (const float*)d_in[2];
    const float* flow  = (const float*)d_in[3];
    const float* w1    = (const float*)d_in[4];
    const float* b1    = (const float*)d_in[5];
    const float* w2    = (const float*)d_in[6];
    const float* b2    = (const float*)d_in[7];
    const float* w3    = (const float*)d_in[8];
    const float* b3    = (const float*)d_in[9];
    const float* w4    = (const float*)d_in[10];
    const float* b4    = (const float*)d_in[11];
    const float* wt    = (const float*)d_in[12];
    const float* bias  = (const float*)d_in[13];
    float* out = (float*)d_out;

    char* ws = (char*)d_ws;
    // ws layout (total <= 91,579,392 B, same as prior passing rounds):
    //   region0 [0, 56.6M)   : X1p (41.9M packed concat input) -> o4 f32 (56.6M)
    //   buf1    @56,623,104  : o1p -> o3p                      (16.8M)
    //   buf2    @73,400,320  : o2p -> xq                       (16.8M)
    //   weights @90,177,536  : Apack, W1h/l(160), W2-4 h/l, b4p
    u16*   X1p  = (u16*)(ws);
    float* o4   = (float*)(ws);
    u16*   buf1 = (u16*)(ws + 56623104);
    u16*   buf2 = (u16*)(ws + 73400320);
    u16* Apack = (u16*)(ws + 90177536);
    u16* W1h = (u16*)(ws + 90251264);
    u16* W1l = (u16*)(ws + 90435584);
    u16* W2h = (u16*)(ws + 90619904);
    u16* W2l = (u16*)(ws + 90693632);
    u16* W3h = (u16*)(ws + 90767360);
    u16* W3l = (u16*)(ws + 90841088);
    u16* W4h = (u16*)(ws + 90914816);
    u16* W4l = (u16*)(ws + 91209728);
    float* b4p = (float*)(ws + 91504640);

    const dim3 blk(256);

    // ---- weight prep ----
    split_w_k<<<dim3((64 * 9 * 160 + 255) / 256), blk, 0, stream>>>(w1, W1h, W1l, 64, 64, 130, 160);
    split_w_k<<<dim3((64 * 9 * 64 + 255) / 256), blk, 0, stream>>>(w2, W2h, W2l, 64, 64, 64, 64);
    split_w_k<<<dim3((64 * 9 * 64 + 255) / 256), blk, 0, stream>>>(w3, W3h, W3l, 64, 64, 64, 64);
    split_w_k<<<dim3((256 * 9 * 64 + 255) / 256), blk, 0, stream>>>(w4, W4h, W4l, 216, 256, 64, 64);
    pad_bias_k<<<dim3(1), blk, 0, stream>>>(b4, b4p);
    pack_dw_k<<<dim3(144), blk, 0, stream>>>(wt, Apack);

    // pack cat(xw,xc,flow) -> X1p (160-ch records)
    pack_x_k<160><<<dim3(BB * HW / 256), blk, 0, stream>>>(xw, xc, flow, X1p);
    // conv1: 160(130) -> 64, lrelu, packed out @ buf1  (16x4 tiles)
    conv_pk_k<3, 1, 0, true, true, 2><<<dim3(256, 1, BB), blk, 0, stream>>>(
        X1p, W1h, W1l, b1, nullptr, buf1, 64);
    // conv2: 64 -> 64, lrelu, packed out @ buf2
    conv_pk_k<1, 2, 0, true, true, 2><<<dim3(256, 1, BB), blk, 0, stream>>>(
        buf1, W2h, W2l, b2, nullptr, buf2, 64);
    // conv3: 64 -> 64, lrelu, packed out @ buf1 (o1p dead)
    conv_pk_k<1, 2, 0, true, true, 2><<<dim3(256, 1, BB), blk, 0, stream>>>(
        buf2, W3h, W3l, b3, nullptr, buf1, 64);
    // x -> channel-quad layout @ buf2 (o2p dead after conv3)
    transpose_xq_k<<<dim3(BB * 16 * HW / 256), blk, 0, stream>>>(x, (float4*)buf2);
    // conv4: 64 -> 216 (pad 256), no act, f32 out @ region0 (X1p dead)
    conv_pk_k<1, 2, 1, false, false, 1><<<dim3(128, 2, BB), blk, 0, stream>>>(
        buf1, W4h, W4l, b4p, o4, nullptr, 216);

    // deform: 16-px blocks
    deform_fused_k<<<dim3(BB * HW / 16), blk, 0, stream>>>(
        (const float4*)buf2, o4, flow, (const uint4*)Apack, bias, out);
}

// Round 11
// 276.508 us; speedup vs baseline: 1.2428x; 1.2428x over previous
//
#include <hip/hip_runtime.h>
#include <math.h>

#define HH 128
#define WW 128
#define BB 4
#define HW (HH*WW)

typedef unsigned short u16;
typedef unsigned int u32;
typedef __bf16 bf16x8 __attribute__((ext_vector_type(8)));
typedef float f32x4 __attribute__((ext_vector_type(4)));

__device__ __forceinline__ u16 f2bf(float x) {
    u32 u = __float_as_uint(x);
    return (u16)((u + 0x7fffu + ((u >> 16) & 1u)) >> 16);
}
__device__ __forceinline__ float bf2f(u16 h) {
    return __uint_as_float(((u32)h) << 16);
}
__device__ __forceinline__ bf16x8 ld8(const u16* p) {
    union { uint4 u; bf16x8 v; } c;
    c.u = *(const uint4*)p;
    return c.v;
}
__device__ __forceinline__ bf16x8 cvt8(uint4 u) {
    union { uint4 u; bf16x8 v; } c;
    c.u = u;
    return c.v;
}

// ---------------------------------------------------------------------------
// Weight split-prep: src [OC][CIN][3][3] f32 -> dh/dl [OCpad][9][CINpad] bf16
// ---------------------------------------------------------------------------
__global__ void split_w_k(const float* __restrict__ src, u16* __restrict__ dh,
                          u16* __restrict__ dl, int OC, int OCpad, int CIN, int CINpad)
{
    const int i = blockIdx.x * 256 + threadIdx.x;
    const int tot = OCpad * 9 * CINpad;
    if (i >= tot) return;
    const int oc = i / (9 * CINpad);
    const int r = i - oc * 9 * CINpad;
    const int tap = r / CINpad;
    const int cin = r - tap * CINpad;
    float v = 0.f;
    if (oc < OC && cin < CIN) v = src[((size_t)oc * CIN + cin) * 9 + tap];
    const u16 h = f2bf(v);
    dh[i] = h;
    dl[i] = f2bf(v - bf2f(h));
}

__global__ void pad_bias_k(const float* __restrict__ b, float* __restrict__ bp)
{
    const int i = blockIdx.x * 256 + threadIdx.x;
    if (i < 256) bp[i] = (i < 216) ? b[i] : 0.f;
}

// ---------------------------------------------------------------------------
// Deform weight [O=64][C=64][3][3] -> bf16 A-fragments for 16x16x32 MFMA:
// Apack u16[kk(18)][fq(4)][m(4)][fr(16)][jj(8)]
// ---------------------------------------------------------------------------
__global__ void pack_dw_k(const float* __restrict__ wt, u16* __restrict__ Apack)
{
    const int i = blockIdx.x * 256 + threadIdx.x;   // 36864
    if (i >= 36864) return;
    const int jj = i & 7;
    const int fr = (i >> 3) & 15;
    const int m  = (i >> 7) & 3;
    const int fq = (i >> 9) & 3;
    const int kk = i >> 11;
    const int oc = m * 16 + fr;
    const int j  = kk * 32 + fq * 8 + jj;
    const int tap = j >> 3, c = j & 7;
    const int g = tap / 9, kt = tap - g * 9;
    const int ch = g * 8 + c;
    Apack[i] = f2bf(wt[((size_t)oc * 64 + ch) * 9 + kt]);
}

// ---------------------------------------------------------------------------
// Pack concat(xw 64, xc 64, flow 2, zeros) into split-bf16 records:
// dst[b*HW+px][CREC*2 u16], ch c at (c>>5)*64 + ((c>>3)&3)*16 + (c&7), lo +8.
// ---------------------------------------------------------------------------
template<int CREC>
__global__ __launch_bounds__(256) void pack_x_k(
    const float* __restrict__ A, const float* __restrict__ B2,
    const float* __restrict__ C3, u16* __restrict__ dst)
{
    const int i = blockIdx.x * 256 + threadIdx.x;   // b*HW + px
    const int b = i >> 14;
    const int px = i & 16383;
    u16* rec = dst + (size_t)i * (CREC * 2);

#pragma unroll
    for (int g = 0; g < CREC / 32; ++g) {
#pragma unroll
        for (int cb = 0; cb < 4; ++cb) {
            u32 hwv[4], lwv[4];
#pragma unroll
            for (int p = 0; p < 4; ++p) {
                float v[2];
#pragma unroll
                for (int e = 0; e < 2; ++e) {
                    const int c = g * 32 + cb * 8 + p * 2 + e;
                    float vv;
                    if (c < 64)       vv = A[((size_t)(b * 64 + c)) * HW + px];
                    else if (c < 128) vv = B2[((size_t)(b * 64 + c - 64)) * HW + px];
                    else if (c < 130) vv = C3[((size_t)(b * 2 + c - 128)) * HW + px];
                    else              vv = 0.f;
                    v[e] = vv;
                }
                const u16 h0 = f2bf(v[0]), h1 = f2bf(v[1]);
                const u16 l0 = f2bf(v[0] - bf2f(h0)), l1 = f2bf(v[1] - bf2f(h1));
                hwv[p] = (u32)h0 | ((u32)h1 << 16);
                lwv[p] = (u32)l0 | ((u32)l1 << 16);
            }
            uint4 H; H.x = hwv[0]; H.y = hwv[1]; H.z = hwv[2]; H.w = hwv[3];
            uint4 L; L.x = lwv[0]; L.y = lwv[1]; L.z = lwv[2]; L.w = lwv[3];
            *(uint4*)(rec + g * 64 + cb * 16)     = H;
            *(uint4*)(rec + g * 64 + cb * 16 + 8) = L;
        }
    }
}

// ---------------------------------------------------------------------------
// MFMA 3x3 conv on packed split-bf16 input (round-9 known-good).
// MODE 0 (conv1-3): tile 16x4, 64 oc. MODE 1 (conv4): tile 16x8, 128 oc,
// ping/pong A prefetch, __launch_bounds__(256,1) [(256,2) caps VGPR=128].
// ---------------------------------------------------------------------------
template<int NCHUNK, int KGLAST, int MODE, bool RELU, bool PACKOUT, int MINW>
__global__ __launch_bounds__(256, MINW) void conv_pk_k(
    const u16* __restrict__ Xp, const u16* __restrict__ Wh, const u16* __restrict__ Wl,
    const float* __restrict__ bias, float* __restrict__ outf, u16* __restrict__ outp,
    int OCreal)
{
    const int ROWS = (MODE == 1) ? 8 : 4;
    const int NPX = (ROWS + 2) * 18;
    __shared__ u16 Xs[NPX * 136];
    const int CINpad = (NCHUNK - 1) * 64 + KGLAST * 32;
    const int CRECU16 = CINpad * 2;

    const int tile = blockIdx.x;
    const int h0 = (tile >> 3) * ROWS;
    const int w0 = (tile & 7) * 16;
    const int b = blockIdx.z;
    const int t = threadIdx.x;
    const int lane = t & 63, wv = t >> 6;
    const int fr = lane & 15, fq = lane >> 4;

    const int mg = wv >> 1, rg = wv & 1;
    const int mbase = (MODE == 1) ? (blockIdx.y * 8 + mg * 4) : 0;

    f32x4 acc0[4];
    f32x4 acc1[4][4];
    if (MODE == 0) {
        const float4 bv = *(const float4*)(bias + wv * 16 + 4 * fq);
#pragma unroll
        for (int n = 0; n < 4; ++n) {
            acc0[n][0] = bv.x; acc0[n][1] = bv.y; acc0[n][2] = bv.z; acc0[n][3] = bv.w;
        }
    } else {
#pragma unroll
        for (int m = 0; m < 4; ++m) {
            const float4 bv = *(const float4*)(bias + (mbase + m) * 16 + 4 * fq);
#pragma unroll
            for (int n = 0; n < 4; ++n) {
                acc1[m][n][0] = bv.x; acc1[m][n][1] = bv.y;
                acc1[m][n][2] = bv.z; acc1[m][n][3] = bv.w;
            }
        }
    }

    const u16* WhL = Wh + (size_t)fr * 9 * CINpad + 8 * fq;
    const u16* WlL = Wl + (size_t)fr * 9 * CINpad + 8 * fq;

#pragma unroll
    for (int chunk = 0; chunk < NCHUNK; ++chunk) {
        const int nkg = (chunk == NCHUNK - 1) ? KGLAST : 2;
        const int nu = nkg * 8;
        __syncthreads();
        for (int s = t; s < NPX * nu; s += 256) {
            const int px = s / nu, o = s - px * nu;
            const int hy = px / 18, hx = px - hy * 18;
            const int gy = h0 + hy - 1, gx = w0 + hx - 1;
            uint4 v; v.x = 0; v.y = 0; v.z = 0; v.w = 0;
            if (gy >= 0 && gy < HH && gx >= 0 && gx < WW)
                v = *(const uint4*)(Xp + ((size_t)(b * HW + gy * WW + gx)) * CRECU16
                                       + chunk * 128 + o * 8);
            *(uint4*)(Xs + px * 136 + o * 8) = v;
        }
        __syncthreads();

        if (MODE == 0) {
#pragma unroll
            for (int tap = 0; tap < 9; ++tap) {
                const int ky = tap / 3, kx = tap % 3;
#pragma unroll
                for (int kg = 0; kg < 2; ++kg) {
                    if (kg >= nkg) break;
                    const size_t off = (size_t)(wv * 144 + tap) * CINpad + chunk * 64 + kg * 32;
                    const bf16x8 Ah = ld8(WhL + off);
                    const bf16x8 Al = ld8(WlL + off);
#pragma unroll
                    for (int n = 0; n < 4; ++n) {
                        const int hp = (n + ky) * 18 + fr + kx;
                        const u16* Bp = Xs + hp * 136 + kg * 64 + fq * 16;
                        const bf16x8 Bh = ld8(Bp);
                        const bf16x8 Bl = ld8(Bp + 8);
                        acc0[n] = __builtin_amdgcn_mfma_f32_16x16x32_bf16(Ah, Bh, acc0[n], 0, 0, 0);
                        acc0[n] = __builtin_amdgcn_mfma_f32_16x16x32_bf16(Ah, Bl, acc0[n], 0, 0, 0);
                        acc0[n] = __builtin_amdgcn_mfma_f32_16x16x32_bf16(Al, Bh, acc0[n], 0, 0, 0);
                    }
                }
            }
        } else {
            auto PF = [&](int tap, bf16x8 (&Dh)[8], bf16x8 (&Dl)[8]) {
#pragma unroll
                for (int kg = 0; kg < 2; ++kg)
#pragma unroll
                    for (int m = 0; m < 4; ++m) {
                        const size_t off = (size_t)((mbase + m) * 144 + tap) * CINpad
                                         + chunk * 64 + kg * 32;
                        Dh[kg * 4 + m] = ld8(WhL + off);
                        Dl[kg * 4 + m] = ld8(WlL + off);
                    }
            };
            auto CMP = [&](int tap, bf16x8 (&Dh)[8], bf16x8 (&Dl)[8]) {
                const int ky = tap / 3, kx = tap - 3 * ky;
#pragma unroll
                for (int kg = 0; kg < 2; ++kg) {
#pragma unroll
                    for (int n = 0; n < 4; ++n) {
                        const int hp = (rg * 4 + n + ky) * 18 + fr + kx;
                        const u16* Bp = Xs + hp * 136 + kg * 64 + fq * 16;
                        const bf16x8 Bh = ld8(Bp);
                        const bf16x8 Bl = ld8(Bp + 8);
#pragma unroll
                        for (int m = 0; m < 4; ++m) {
                            acc1[m][n] = __builtin_amdgcn_mfma_f32_16x16x32_bf16(Dh[kg * 4 + m], Bh, acc1[m][n], 0, 0, 0);
                            acc1[m][n] = __builtin_amdgcn_mfma_f32_16x16x32_bf16(Dh[kg * 4 + m], Bl, acc1[m][n], 0, 0, 0);
                            acc1[m][n] = __builtin_amdgcn_mfma_f32_16x16x32_bf16(Dl[kg * 4 + m], Bh, acc1[m][n], 0, 0, 0);
                        }
                    }
                }
            };

            bf16x8 PaH[8], PaL[8], PbH[8], PbL[8];
            PF(0, PaH, PaL);
#pragma unroll 1
            for (int tp = 0; tp < 4; ++tp) {
                PF(2 * tp + 1, PbH, PbL);
                CMP(2 * tp, PaH, PaL);
                PF(2 * tp + 2, PaH, PaL);
                CMP(2 * tp + 1, PbH, PbL);
            }
            CMP(8, PaH, PaL);
        }
    }

    if (MODE == 1) {
#pragma unroll
        for (int m = 0; m < 4; ++m)
#pragma unroll
            for (int n = 0; n < 4; ++n)
#pragma unroll
                for (int i = 0; i < 4; ++i) {
                    const int oc = (mbase + m) * 16 + 4 * fq + i;
                    if (oc < OCreal) {
                        float v = acc1[m][n][i];
                        if (RELU) v = (v >= 0.f) ? v : 0.1f * v;
                        outf[((size_t)(b * OCreal + oc)) * HW + (h0 + rg * 4 + n) * WW + w0 + fr] = v;
                    }
                }
    } else if (!PACKOUT) {
#pragma unroll
        for (int n = 0; n < 4; ++n)
#pragma unroll
            for (int i = 0; i < 4; ++i) {
                const int oc = wv * 16 + 4 * fq + i;
                if (oc < OCreal) {
                    float v = acc0[n][i];
                    if (RELU) v = (v >= 0.f) ? v : 0.1f * v;
                    outf[((size_t)(b * OCreal + oc)) * HW + (h0 + n) * WW + w0 + fr] = v;
                }
            }
    } else {
        __syncthreads();
        const int coff = (wv >> 1) * 64 + (((wv << 1) + (fq >> 1)) & 3) * 16 + ((fq & 1) << 2);
#pragma unroll
        for (int n = 0; n < 4; ++n) {
            u16 hh[4], ll[4];
#pragma unroll
            for (int i = 0; i < 4; ++i) {
                float v = acc0[n][i];
                if (RELU) v = (v >= 0.f) ? v : 0.1f * v;
                hh[i] = f2bf(v);
                ll[i] = f2bf(v - bf2f(hh[i]));
            }
            uint2 H, L;
            H.x = (u32)hh[0] | ((u32)hh[1] << 16);
            H.y = (u32)hh[2] | ((u32)hh[3] << 16);
            L.x = (u32)ll[0] | ((u32)ll[1] << 16);
            L.y = (u32)ll[2] | ((u32)ll[3] << 16);
            const int pxe = n * 16 + fr;
            u16* E = Xs + pxe * 136 + coff;
            *(uint2*)E = H;
            *(uint2*)(E + 8) = L;
        }
        __syncthreads();
        for (int i = t; i < 1024; i += 256) {
            const int px = i >> 4, o = i & 15;
            const uint4 v = *(const uint4*)(Xs + px * 136 + o * 8);
            const int gp = (h0 + (px >> 4)) * WW + w0 + (px & 15);
            *(uint4*)(outp + ((size_t)(b * HW + gp)) * 128 + o * 8) = v;
        }
    }
}

// ---------------------------------------------------------------------------
// x [b][64][HW] -> xqb [b][8g][HW] of 8-ch bf16 octs (16 B per (px,g)):
// one corner gather = ONE uint4 load (halves deform gather traffic).
// ---------------------------------------------------------------------------
__global__ __launch_bounds__(256) void pack_xb_k(
    const float* __restrict__ x, uint4* __restrict__ xqb)
{
    const int i = blockIdx.x * 256 + threadIdx.x;   // B*8*HW
    const int pix = i & (HW - 1);
    const int g = (i >> 14) & 7;
    const int b = i >> 17;
    const float* xp = x + ((size_t)(b * 64 + g * 8)) * HW + pix;
    u32 w[4];
#pragma unroll
    for (int c2 = 0; c2 < 4; ++c2) {
        const u16 l = f2bf(xp[(size_t)(2 * c2) * HW]);
        const u16 h = f2bf(xp[(size_t)(2 * c2 + 1) * HW]);
        w[c2] = (u32)l | ((u32)h << 16);
    }
    uint4 v; v.x = w[0]; v.y = w[1]; v.z = w[2]; v.w = w[3];
    xqb[(size_t)(b * 8 + g) * HW + pix] = v;
}

__device__ __forceinline__ unsigned pk_bf16(float lo, float hi) {
    unsigned a = __float_as_uint(lo), b = __float_as_uint(hi);
    return ((a + 0x8000u) >> 16) | ((b + 0x8000u) & 0xffff0000u);
}

// ---------------------------------------------------------------------------
// Fused deform (round-9 structure + bf16-oct gathers). Block = 32 px.
// Phase 1: thread=(px,g): offsets/mask -> 9 taps, 4 x 16B corner loads each,
//          bilinear in f32 (bf16 unpack = shift/mask) -> bf16 into LDS.
// Phase 2: MFMA contraction vs Apack (2 N-tiles). One barrier.
// ---------------------------------------------------------------------------
__global__ __launch_bounds__(256, 4) void deform_fused_k(
    const uint4* __restrict__ xqb, const float* __restrict__ o4,
    const float* __restrict__ flow, const uint4* __restrict__ Apack,
    const float* __restrict__ bias, float* __restrict__ out)
{
    __shared__ u16 sv[32 * 584];   // 37,376 B

    const int bid = blockIdx.x;    // 2048
    const int b = bid >> 9;
    const int pix0 = (bid & 511) << 5;
    const int t = threadIdx.x;

    // ---------------- phase 1: gather (px = t&31, g = t>>5) ----------------
    {
        const int gpx = t & 31, g = t >> 5;
        const int pix = pix0 + gpx;
        const int h = pix >> 7, w = pix & (WW - 1);
        const float fy = flow[((size_t)b * 2 + 1) * HW + pix];
        const float fx = flow[((size_t)b * 2 + 0) * HW + pix];
        const float* ob = o4 + (size_t)b * 216 * HW + pix;
        const uint4* qg = xqb + (size_t)(b * 8 + g) * HW;

        int   code[9];
        float w00[9], w01[9], w10[9], w11[9];

#pragma unroll
        for (int k = 0; k < 9; ++k) {
            const float oy = ob[(size_t)(g * 18 + k * 2) * HW];
            const float ox = ob[(size_t)(g * 18 + k * 2 + 1) * HW];
            float mm = ob[(size_t)(144 + g * 9 + k) * HW];
            mm = __builtin_amdgcn_rcpf(1.f + __expf(-mm));

            const float ay = fabsf(oy), ax = fabsf(ox);
            const float ey = __expf(-2.f * ay), ex = __expf(-2.f * ax);
            float ty = (1.f - ey) * __builtin_amdgcn_rcpf(1.f + ey);
            float tx = (1.f - ex) * __builtin_amdgcn_rcpf(1.f + ex);
            ty = copysignf(ty, oy); tx = copysignf(tx, ox);

            const float ppy = 10.f * ty + fy + (float)(h + k / 3 - 1);
            const float ppx = 10.f * tx + fx + (float)(w + k % 3 - 1);

            const float y0f = floorf(ppy), x0f = floorf(ppx);
            const float ly = ppy - y0f, lx = ppx - x0f;
            const int iy0 = (int)y0f, ix0 = (int)x0f;
            const int iy1 = iy0 + 1,  ix1 = ix0 + 1;

            const float vy0 = (iy0 >= 0 && iy0 < HH) ? 1.f : 0.f;
            const float vy1 = (iy1 >= 0 && iy1 < HH) ? 1.f : 0.f;
            const float vx0 = (ix0 >= 0 && ix0 < WW) ? 1.f : 0.f;
            const float vx1 = (ix1 >= 0 && ix1 < WW) ? 1.f : 0.f;

            const int cy0 = min(max(iy0, 0), HH - 1);
            const int cy1 = min(max(iy1, 0), HH - 1);
            const int cx0 = min(max(ix0, 0), WW - 1);
            const int cx1 = min(max(ix1, 0), WW - 1);

            w00[k] = (1.f - ly) * (1.f - lx) * vy0 * vx0 * mm;
            w01[k] = (1.f - ly) * lx         * vy0 * vx1 * mm;
            w10[k] = ly         * (1.f - lx) * vy1 * vx0 * mm;
            w11[k] = ly         * lx         * vy1 * vx1 * mm;

            code[k] = (cy0 * WW + cx0) | ((cx1 - cx0) << 14) | ((cy1 - cy0) << 15);
        }

        u16* svp = sv + gpx * 584 + g * 72;
#pragma unroll
        for (int k = 0; k < 9; ++k) {
            const int i00 = code[k] & 16383;
            const int i01 = i00 + ((code[k] >> 14) & 1);
            const int i10 = i00 + (((code[k] >> 15) & 1) << 7);
            const int i11 = i10 + ((code[k] >> 14) & 1);

            const uint4 A4 = qg[i00];
            const uint4 B4 = qg[i01];
            const uint4 C4 = qg[i10];
            const uint4 D4 = qg[i11];
            const float W00 = w00[k], W01 = w01[k], W10 = w10[k], W11 = w11[k];

            uint4 P;
            u32 pw[4];
#pragma unroll
            for (int c2 = 0; c2 < 4; ++c2) {
                const u32 aw = (&A4.x)[c2], bw = (&B4.x)[c2];
                const u32 cw = (&C4.x)[c2], dw = (&D4.x)[c2];
                const float alo = __uint_as_float(aw << 16), ahi = __uint_as_float(aw & 0xffff0000u);
                const float blo = __uint_as_float(bw << 16), bhi = __uint_as_float(bw & 0xffff0000u);
                const float clo = __uint_as_float(cw << 16), chi = __uint_as_float(cw & 0xffff0000u);
                const float dlo = __uint_as_float(dw << 16), dhi = __uint_as_float(dw & 0xffff0000u);
                const float slo = W00 * alo + W01 * blo + W10 * clo + W11 * dlo;
                const float shi = W00 * ahi + W01 * bhi + W10 * chi + W11 * dhi;
                pw[c2] = pk_bf16(slo, shi);
            }
            P.x = pw[0]; P.y = pw[1]; P.z = pw[2]; P.w = pw[3];
            *(uint4*)(svp + (size_t)k * 8) = P;
        }
    }
    __syncthreads();

    // ---------------- phase 2: MFMA (wave wv = M-tile) ---------------------
    {
        const int lane = t & 63, wv = t >> 6;
        const int fr = lane & 15, fq = lane >> 4;

        f32x4 acc[2];
#pragma unroll
        for (int n = 0; n < 2; ++n) { acc[n][0] = 0.f; acc[n][1] = 0.f; acc[n][2] = 0.f; acc[n][3] = 0.f; }

#pragma unroll
        for (int kk = 0; kk < 18; ++kk) {
            const bf16x8 A = cvt8(Apack[((kk * 4 + fq) * 4 + wv) * 16 + fr]);
#pragma unroll
            for (int n = 0; n < 2; ++n) {
                const bf16x8 Bf = ld8(sv + (size_t)(n * 16 + fr) * 584 + kk * 32 + fq * 8);
                acc[n] = __builtin_amdgcn_mfma_f32_16x16x32_bf16(A, Bf, acc[n], 0, 0, 0);
            }
        }

        const float4 bv = *(const float4*)(bias + wv * 16 + 4 * fq);
        const float bb[4] = { bv.x, bv.y, bv.z, bv.w };
#pragma unroll
        for (int n = 0; n < 2; ++n) {
            const int pix = pix0 + n * 16 + fr;
#pragma unroll
            for (int i = 0; i < 4; ++i) {
                const int oc = wv * 16 + 4 * fq + i;
                out[((size_t)b * 64 + oc) * HW + pix] = acc[n][i] + bb[i];
            }
        }
    }
}

// ---------------------------------------------------------------------------
extern "C" void kernel_launch(void* const* d_in, const int* in_sizes, int n_in,
                              void* d_out, int out_size, void* d_ws, size_t ws_size,
                              hipStream_t stream)
{
    const float* x     = (const float*)d_in[0];
    const float* xw    = (const float*)d_in[1];
    const float* xc    = (const float*)d_in[2];
    const float* flow  = (const float*)d_in[3];
    const float* w1    = (const float*)d_in[4];
    const float* b1    = (const float*)d_in[5];
    const float* w2    = (const float*)d_in[6];
    const float* b2    = (const float*)d_in[7];
    const float* w3    = (const float*)d_in[8];
    const float* b3    = (const float*)d_in[9];
    const float* w4    = (const float*)d_in[10];
    const float* b4    = (const float*)d_in[11];
    const float* wt    = (const float*)d_in[12];
    const float* bias  = (const float*)d_in[13];
    float* out = (float*)d_out;

    char* ws = (char*)d_ws;
    // ws layout (total <= 91,579,392 B, same as prior passing rounds):
    //   region0 [0, 56.6M)   : X1p (41.9M packed concat input) -> o4 f32 (56.6M)
    //   buf1    @56,623,104  : o1p -> o3p                      (16.8M)
    //   buf2    @73,400,320  : o2p -> xqb (bf16 octs, 8.4M)    (16.8M)
    //   weights @90,177,536  : Apack, W1h/l(160), W2-4 h/l, b4p
    u16*   X1p  = (u16*)(ws);
    float* o4   = (float*)(ws);
    u16*   buf1 = (u16*)(ws + 56623104);
    u16*   buf2 = (u16*)(ws + 73400320);
    u16* Apack = (u16*)(ws + 90177536);
    u16* W1h = (u16*)(ws + 90251264);
    u16* W1l = (u16*)(ws + 90435584);
    u16* W2h = (u16*)(ws + 90619904);
    u16* W2l = (u16*)(ws + 90693632);
    u16* W3h = (u16*)(ws + 90767360);
    u16* W3l = (u16*)(ws + 90841088);
    u16* W4h = (u16*)(ws + 90914816);
    u16* W4l = (u16*)(ws + 91209728);
    float* b4p = (float*)(ws + 91504640);

    const dim3 blk(256);

    // ---- weight prep ----
    split_w_k<<<dim3((64 * 9 * 160 + 255) / 256), blk, 0, stream>>>(w1, W1h, W1l, 64, 64, 130, 160);
    split_w_k<<<dim3((64 * 9 * 64 + 255) / 256), blk, 0, stream>>>(w2, W2h, W2l, 64, 64, 64, 64);
    split_w_k<<<dim3((64 * 9 * 64 + 255) / 256), blk, 0, stream>>>(w3, W3h, W3l, 64, 64, 64, 64);
    split_w_k<<<dim3((256 * 9 * 64 + 255) / 256), blk, 0, stream>>>(w4, W4h, W4l, 216, 256, 64, 64);
    pad_bias_k<<<dim3(1), blk, 0, stream>>>(b4, b4p);
    pack_dw_k<<<dim3(144), blk, 0, stream>>>(wt, Apack);

    // pack cat(xw,xc,flow) -> X1p (160-ch records)
    pack_x_k<160><<<dim3(BB * HW / 256), blk, 0, stream>>>(xw, xc, flow, X1p);
    // conv1: 160(130) -> 64, lrelu, packed out @ buf1  (16x4 tiles)
    conv_pk_k<3, 1, 0, true, true, 2><<<dim3(256, 1, BB), blk, 0, stream>>>(
        X1p, W1h, W1l, b1, nullptr, buf1, 64);
    // conv2: 64 -> 64, lrelu, packed out @ buf2
    conv_pk_k<1, 2, 0, true, true, 2><<<dim3(256, 1, BB), blk, 0, stream>>>(
        buf1, W2h, W2l, b2, nullptr, buf2, 64);
    // conv3: 64 -> 64, lrelu, packed out @ buf1 (o1p dead)
    conv_pk_k<1, 2, 0, true, true, 2><<<dim3(256, 1, BB), blk, 0, stream>>>(
        buf2, W3h, W3l, b3, nullptr, buf1, 64);
    // x -> bf16 channel-oct layout @ buf2 (o2p dead after conv3)
    pack_xb_k<<<dim3(BB * 8 * HW / 256), blk, 0, stream>>>(x, (uint4*)buf2);
    // conv4: 64 -> 216 (pad 256), no act, f32 out @ region0 (X1p dead)
    conv_pk_k<1, 2, 1, false, false, 1><<<dim3(128, 2, BB), blk, 0, stream>>>(
        buf1, W4h, W4l, b4p, o4, nullptr, 216);

    // deform: 32-px blocks (round-9 structure), bf16-oct gathers
    deform_fused_k<<<dim3(BB * HW / 32), blk, 0, stream>>>(
        (const uint4*)buf2, o4, flow, (const uint4*)Apack, bias, out);
}